// Round 8
// baseline (51.096 us; speedup 1.0000x reference)
//
#include <hip/hip_runtime.h>
#include <math.h>

// Problem constants: B=4, C=128, H=W=96, E=4, C8=16, scale=2 (baked in)
#define Bn 4
#define Cc 128
#define Hh 96
#define Ww 96
#define H2c 192
#define W2c 192
#define HW (Hh*Ww)

// Workspace layout:
//   floats: [WC_OFF,+4*2048) Wc_t[cls][c][o] ; [WE_OFF,+4*2048) We[cls][c][o]
//           [TAP_OFF,+16) per-class {tx,ty,Dx,Dy}
//   ushort (bf16) at float-offset M_OFF: M[cls][c_out][128]  (folded We*Wc+I)
#define WC_OFF 0
#define WE_OFF (4*2048)
#define TAP_OFF (8*2048)
#define M_OFF  16640          // float offset; byte 66560 (16B aligned)

typedef float  f32x4  __attribute__((ext_vector_type(4)));
typedef short  s16x8  __attribute__((ext_vector_type(8)));

__device__ __forceinline__ unsigned f2bf(float f) {
    unsigned u = __float_as_uint(f);
    return (u + 0x7FFFu + ((u >> 16) & 1u)) >> 16;   // RNE to bf16
}

// ---------------------------------------------------------------------------
// K1: per-class tiny MLP -> routing/offsets; mix expert weights; tap constants.
__global__ __launch_bounds__(256) void k1_mix(
    const float* __restrict__ wcomp, const float* __restrict__ wexp,
    const float* __restrict__ bw1, const float* __restrict__ bb1,
    const float* __restrict__ bw2, const float* __restrict__ bb2,
    const float* __restrict__ rw,  const float* __restrict__ rb,
    const float* __restrict__ ow,  const float* __restrict__ ob,
    float* __restrict__ ws)
{
    __shared__ float e1[64], e2[64], rr[4], of[2];
    const int tid   = threadIdx.x;
    const int cls   = blockIdx.x >> 4;
    const int chunk = blockIdx.x & 15;
    const float chv = (cls & 2) ? 0.25f : -0.25f;
    const float cwv = (cls & 1) ? 0.25f : -0.25f;

    if (tid < 64) {
        float h = bw1[tid*3+0]*0.5f + bw1[tid*3+1]*chv + bw1[tid*3+2]*cwv + bb1[tid];
        e1[tid] = fmaxf(h, 0.f);
    }
    __syncthreads();
    if (tid < 64) {
        float s = bb2[tid];
        for (int i = 0; i < 64; ++i) s += bw2[tid*64+i]*e1[i];
        e2[tid] = fmaxf(s, 0.f);
    }
    __syncthreads();
    if (tid < 6) {
        if (tid < 4) {
            float s = rb[tid];
            for (int i = 0; i < 64; ++i) s += rw[tid*64+i]*e2[i];
            rr[tid] = 1.f/(1.f+expf(-s));
        } else {
            const int d = tid - 4;
            float s = ob[d];
            for (int i = 0; i < 64; ++i) s += ow[d*64+i]*e2[i];
            of[d] = s;
        }
    }
    __syncthreads();
    const float r0 = rr[0], r1 = rr[1], r2 = rr[2], r3 = rr[3];

    if (tid < 128) {
        const int idx = chunk*128 + tid;
        const int o = idx >> 7, c = idx & 127;
        const float v = r0*wcomp[idx] + r1*wcomp[2048+idx]
                      + r2*wcomp[4096+idx] + r3*wcomp[6144+idx];
        ws[WC_OFF + cls*2048 + c*16 + o] = v;     // transposed [c][o]
    } else {
        const int idx = chunk*128 + (tid - 128);
        ws[WE_OFF + cls*2048 + idx] =             // native [c][o]
            r0*wexp[idx] + r1*wexp[2048+idx] + r2*wexp[4096+idx] + r3*wexp[6144+idx];
    }
    if (chunk == 0 && tid == 0) {
        const float fx = cwv + of[0];
        const float fy = chv + of[1];
        const float Dx = floorf(fx), Dy = floorf(fy);
        ws[TAP_OFF + cls*4 + 0] = fx - Dx;
        ws[TAP_OFF + cls*4 + 1] = fy - Dy;
        ws[TAP_OFF + cls*4 + 2] = Dx;
        ws[TAP_OFF + cls*4 + 3] = Dy;
    }
}

// ---------------------------------------------------------------------------
// K1b: fold M[cls] = We_mix * Wc_mix + I, store bf16 row-major [c_out][c_in].
__global__ __launch_bounds__(256) void k1b_fold(
    const float* __restrict__ wsr, unsigned short* __restrict__ Mw)
{
    const int t   = blockIdx.x*256 + threadIdx.x;    // 0..16383
    const int cls = t >> 12;
    const int rem = t & 4095;
    const int co  = rem >> 5;            // c_out 0..127
    const int ci0 = (rem & 31) * 4;      // c_in base
    const float* we = wsr + WE_OFF + cls*2048 + co*16;

    float m[4];
    #pragma unroll
    for (int q = 0; q < 4; ++q) {
        const float* wc = wsr + WC_OFF + cls*2048 + (ci0+q)*16;
        float s = 0.f;
        #pragma unroll
        for (int o = 0; o < 16; ++o) s += we[o]*wc[o];
        if (co == ci0 + q) s += 1.f;     // residual identity folded in
        m[q] = s;
    }
    uint2 v;
    v.x = f2bf(m[0]) | (f2bf(m[1]) << 16);
    v.y = f2bf(m[2]) | (f2bf(m[3]) << 16);
    *reinterpret_cast<uint2*>(Mw + (size_t)cls*16384 + co*128 + ci0) = v;
}

// Edge remap (verified rounds 1-7).
__device__ __forceinline__ void remap_axis(int c0, int last, float w0, float w1,
                                           int& base, float& a0, float& a1)
{
    base = min(max(c0, 0), last - 1);
    if (c0 >= 0 && c0 < last) { a0 = w0;  a1 = w1;  }
    else if (c0 == -1)        { a0 = w1;  a1 = 0.f; }
    else if (c0 == last)      { a0 = 0.f; a1 = w0;  }
    else                      { a0 = 0.f; a1 = 0.f; }
}

// ---------------------------------------------------------------------------
// K2: fused gather + (M+I)@fea via MFMA, deep-MLP producer.
// 2304 blocks x 256 threads (4 waves). Block = 64 half-res pixels of ONE
// class (round-4 tiling/XCD-swizzle). Producer: tap loads staged through
// live arrays in two 64-load batches (vmcnt-deep) before any use. GEMM:
// wave grp owns out-channels [32g,32g+32); A = M rows (hoisted loads),
// B = fea bf16 via swizzled LDS; 32 x mfma_f32_16x16x32_bf16.
__global__ __launch_bounds__(256) void k2_mfma(
    const float* __restrict__ x, const float* __restrict__ wsr,
    const unsigned short* __restrict__ Mw, float* __restrict__ out)
{
    __shared__ __align__(16) unsigned short lF[64*128];   // 16 KB, swizzled

    const int tid = threadIdx.x;
    const int xl  = tid & 63;
    const int grp = tid >> 6;

    // XCD-paired swizzle (round 4): 2304 = 8 XCDs * 288
    const int n = blockIdx.x;
    const int w = (n & 7) * 288 + (n >> 3);
    const int px_ = w & 1, py = (w >> 1) & 1;
    const int w2 = w >> 2;
    const int tile = w2 % 144;
    const int b    = w2 / 144;
    const int cls  = (py << 1) | px_;

    // ---- A fragments first: 8 independent 16B loads, L2-hot, hoisted ----
    const unsigned short* Mc = Mw + (size_t)cls*16384;
    s16x8 a[2][4];
    #pragma unroll
    for (int t = 0; t < 2; ++t)
        #pragma unroll
        for (int kk = 0; kk < 4; ++kk) {
            const int row = 32*grp + 16*t + (xl & 15);
            a[t][kk] = *reinterpret_cast<const s16x8*>(
                Mc + row*128 + kk*32 + (xl >> 4)*8);
        }

    // ---- taps for this thread's pixel ----
    const int pix = tile*64 + xl;
    const int j = pix / 96;
    const int i = pix - j*96;

    const float tx = wsr[TAP_OFF + cls*4 + 0];
    const float ty = wsr[TAP_OFF + cls*4 + 1];
    const int   Dx = (int)wsr[TAP_OFF + cls*4 + 2];
    const int   Dy = (int)wsr[TAP_OFF + cls*4 + 3];
    int cb, rbw; float ax0, ax1, ay0, ay1;
    remap_axis(i + Dx, Ww - 1, 1.f - tx, tx, cb,  ax0, ax1);
    remap_axis(j + Dy, Hh - 1, 1.f - ty, ty, rbw, ay0, ay1);
    const float w00 = ay0*ax0, w01 = ay0*ax1, w10 = ay1*ax0, w11 = ay1*ax1;
    const float* xb = x + (size_t)b*Cc*HW + rbw*Ww + cb;

    // ---- producer: two 64-load batches staged in live arrays ----
    #pragma unroll
    for (int h = 0; h < 2; ++h) {
        float t00[16], t01[16], t10[16], t11[16];
        #pragma unroll
        for (int k = 0; k < 16; ++k) {
            const float* p = xb + (size_t)(grp*32 + h*16 + k)*HW;
            t00[k] = p[0];
            t01[k] = p[1];
            t10[k] = p[Ww];
            t11[k] = p[Ww+1];
        }
        #pragma unroll
        for (int k = 0; k < 16; k += 4) {
            const float f0 = w00*t00[k  ] + w01*t01[k  ] + w10*t10[k  ] + w11*t11[k  ];
            const float f1 = w00*t00[k+1] + w01*t01[k+1] + w10*t10[k+1] + w11*t11[k+1];
            const float f2 = w00*t00[k+2] + w01*t01[k+2] + w10*t10[k+2] + w11*t11[k+2];
            const float f3 = w00*t00[k+3] + w01*t01[k+3] + w10*t10[k+3] + w11*t11[k+3];
            uint2 v;
            v.x = f2bf(f0) | (f2bf(f1) << 16);
            v.y = f2bf(f2) | (f2bf(f3) << 16);
            const int c = grp*32 + h*16 + k;
            int byte = xl*256 + c*2;
            byte ^= (xl & 7) << 4;
            *reinterpret_cast<uint2*>(reinterpret_cast<char*>(lF) + byte) = v;
        }
    }
    __syncthreads();

    // ---- GEMM: D[128 x 64px] = M @ fea  (residual folded into M) ----
    f32x4 acc[2][4];
    #pragma unroll
    for (int t = 0; t < 2; ++t)
        #pragma unroll
        for (int nn = 0; nn < 4; ++nn) acc[t][nn] = (f32x4){0.f, 0.f, 0.f, 0.f};

    #pragma unroll
    for (int kk = 0; kk < 4; ++kk) {
        #pragma unroll
        for (int nn = 0; nn < 4; ++nn) {
            int byte = (nn*16 + (xl & 15))*256 + kk*64 + (xl >> 4)*16;
            byte ^= (xl & 7) << 4;
            const s16x8 bf = *reinterpret_cast<const s16x8*>(
                reinterpret_cast<const char*>(lF) + byte);
            acc[0][nn] = __builtin_amdgcn_mfma_f32_16x16x32_bf16(a[0][kk], bf, acc[0][nn], 0, 0, 0);
            acc[1][nn] = __builtin_amdgcn_mfma_f32_16x16x32_bf16(a[1][kk], bf, acc[1][nn], 0, 0, 0);
        }
    }

    // ---- store (round-4/7 pattern, L2-merged with partner class) ----
    #pragma unroll
    for (int t = 0; t < 2; ++t)
        #pragma unroll
        for (int nn = 0; nn < 4; ++nn) {
            const int pix2 = tile*64 + nn*16 + (xl & 15);
            const int j2 = pix2 / 96;
            const int i2 = pix2 - j2*96;
            const int yg = 2*j2 + py;
            const int xg = 2*i2 + px_;
            const int ch0 = 32*grp + 16*t + (xl >> 4)*4;
            float* op = out + ((size_t)(b*Cc + ch0)*H2c + yg)*W2c + xg;
            #pragma unroll
            for (int r = 0; r < 4; ++r)
                op[(size_t)r*(H2c*W2c)] = acc[t][nn][r];
        }
}

extern "C" void kernel_launch(void* const* d_in, const int* in_sizes, int n_in,
                              void* d_out, int out_size, void* d_ws, size_t ws_size,
                              hipStream_t stream) {
    const float* x     = (const float*)d_in[0];
    const float* wcomp = (const float*)d_in[1];
    const float* wexp  = (const float*)d_in[2];
    const float* bw1   = (const float*)d_in[3];
    const float* bb1   = (const float*)d_in[4];
    const float* bw2   = (const float*)d_in[5];
    const float* bb2   = (const float*)d_in[6];
    const float* rw    = (const float*)d_in[7];
    const float* rb    = (const float*)d_in[8];
    const float* ow    = (const float*)d_in[9];
    const float* ob    = (const float*)d_in[10];
    float* out = (float*)d_out;
    float* ws  = (float*)d_ws;
    unsigned short* Mw = (unsigned short*)(ws + M_OFF);   // ~194 KB total used

    k1_mix<<<64, 256, 0, stream>>>(wcomp, wexp, bw1, bb1, bw2, bb2, rw, rb, ow, ob, ws);
    k1b_fold<<<64, 256, 0, stream>>>(ws, Mw);
    k2_mfma<<<2304, 256, 0, stream>>>(x, ws, Mw, out);
}